// Round 5
// baseline (3426.187 us; speedup 1.0000x reference)
//
#include <hip/hip_runtime.h>
#include <hip/hip_bf16.h>
#include <math.h>

#define S 2048
#define DM 2048
#define NH 16
#define HD 128
#define RD 64
#define LR 1024
#define TOPK 512

// ---------------------------------------------------------------- fp32 GEMM
// C[M,N] = (A[M,K] @ W[N,K]^T + bias) * alpha   (row-major everywhere)
#define GT_M 128
#define GT_N 64
#define GT_K 16

__global__ __launch_bounds__(256)
void k_gemm(const float* __restrict__ A, const float* __restrict__ W,
            const float* __restrict__ bias, float* __restrict__ C,
            int M, int N, int K, float alpha)
{
    __shared__ float As[GT_K][GT_M + 4];
    __shared__ float Ws[GT_K][GT_N + 4];
    const int tid = threadIdx.x;
    const int tx = tid & 15, ty = tid >> 4;
    const int m0 = blockIdx.y * GT_M, n0 = blockIdx.x * GT_N;

    float acc[8][4];
#pragma unroll
    for (int i = 0; i < 8; ++i)
#pragma unroll
        for (int j = 0; j < 4; ++j) acc[i][j] = 0.f;

    const int ar = tid >> 1;          // 0..127
    const int ak = (tid & 1) << 3;    // 0 / 8
    const int wr = tid >> 2;          // 0..63
    const int wk = (tid & 3) << 2;    // 0,4,8,12

    for (int kk = 0; kk < K; kk += GT_K) {
        float4 v0 = *(const float4*)&A[(size_t)(m0 + ar) * K + kk + ak];
        float4 v1 = *(const float4*)&A[(size_t)(m0 + ar) * K + kk + ak + 4];
        float4 w0 = make_float4(0.f, 0.f, 0.f, 0.f);
        if (n0 + wr < N) w0 = *(const float4*)&W[(size_t)(n0 + wr) * K + kk + wk];
        __syncthreads();
        As[ak + 0][ar] = v0.x; As[ak + 1][ar] = v0.y; As[ak + 2][ar] = v0.z; As[ak + 3][ar] = v0.w;
        As[ak + 4][ar] = v1.x; As[ak + 5][ar] = v1.y; As[ak + 6][ar] = v1.z; As[ak + 7][ar] = v1.w;
        Ws[wk + 0][wr] = w0.x; Ws[wk + 1][wr] = w0.y; Ws[wk + 2][wr] = w0.z; Ws[wk + 3][wr] = w0.w;
        __syncthreads();
#pragma unroll
        for (int k = 0; k < GT_K; ++k) {
            float a0[8], b0[4];
            *(float4*)&a0[0] = *(const float4*)&As[k][ty * 8];
            *(float4*)&a0[4] = *(const float4*)&As[k][ty * 8 + 4];
            *(float4*)&b0[0] = *(const float4*)&Ws[k][tx * 4];
#pragma unroll
            for (int i = 0; i < 8; ++i)
#pragma unroll
                for (int j = 0; j < 4; ++j)
                    acc[i][j] = fmaf(a0[i], b0[j], acc[i][j]);
        }
    }
    const int n = n0 + tx * 4;
    if (n < N) {
#pragma unroll
        for (int i = 0; i < 8; ++i) {
            const int m = m0 + ty * 8 + i;
            float4 o;
            o.x = (acc[i][0] + bias[n + 0]) * alpha;
            o.y = (acc[i][1] + bias[n + 1]) * alpha;
            o.z = (acc[i][2] + bias[n + 2]) * alpha;
            o.w = (acc[i][3] + bias[n + 3]) * alpha;
            *(float4*)&C[(size_t)m * N + n] = o;
        }
    }
}

// ---------------------------------------------------------------- fp64 GEMM (indexer chain)
// C64[M,N] = (A[M,K] @ W32[N,K]^T + bias32) * alpha, accumulated in double.
template<typename TA>
__global__ __launch_bounds__(256)
void k_gemm64(const TA* __restrict__ A, const float* __restrict__ W,
              const float* __restrict__ bias, double* __restrict__ C,
              int M, int N, int K, double alpha)
{
    __shared__ double As[16][66];
    __shared__ double Ws[16][66];
    const int tid = threadIdx.x;
    const int tx = tid & 15, ty = tid >> 4;
    const int m0 = blockIdx.y * 64, n0 = blockIdx.x * 64;
    const int r = tid >> 2, k4 = (tid & 3) << 2;

    double acc[4][4];
#pragma unroll
    for (int i = 0; i < 4; ++i)
#pragma unroll
        for (int j = 0; j < 4; ++j) acc[i][j] = 0.0;

    for (int kk = 0; kk < K; kk += 16) {
        double av[4], wv[4];
        const TA* ap = &A[(size_t)(m0 + r) * K + kk + k4];
#pragma unroll
        for (int i = 0; i < 4; ++i) av[i] = (double)ap[i];
        if (n0 + r < N) {
            const float* wp = &W[(size_t)(n0 + r) * K + kk + k4];
#pragma unroll
            for (int i = 0; i < 4; ++i) wv[i] = (double)wp[i];
        } else {
#pragma unroll
            for (int i = 0; i < 4; ++i) wv[i] = 0.0;
        }
        __syncthreads();
#pragma unroll
        for (int i = 0; i < 4; ++i) { As[k4 + i][r] = av[i]; Ws[k4 + i][r] = wv[i]; }
        __syncthreads();
#pragma unroll 4
        for (int k = 0; k < 16; ++k) {
            double a[4], b[4];
#pragma unroll
            for (int i = 0; i < 4; ++i) a[i] = As[k][ty * 4 + i];
#pragma unroll
            for (int j = 0; j < 4; ++j) b[j] = Ws[k][tx * 4 + j];
#pragma unroll
            for (int i = 0; i < 4; ++i)
#pragma unroll
                for (int j = 0; j < 4; ++j)
                    acc[i][j] = fma(a[i], b[j], acc[i][j]);
        }
    }
    const int n = n0 + tx * 4;
    if (n < N) {
#pragma unroll
        for (int i = 0; i < 4; ++i) {
            const int m = m0 + ty * 4 + i;
#pragma unroll
            for (int j = 0; j < 4; ++j)
                C[(size_t)m * N + n + j] = (acc[i][j] + (double)bias[n + j]) * alpha;
        }
    }
}

// ---------------------------------------------------------------- RMSNorm fp32
__global__ __launch_bounds__(256)
void k_rmsnorm(const float* __restrict__ X, const float* __restrict__ w,
               float* __restrict__ Y, int D)
{
    const int row = blockIdx.x;
    const float* x = X + (size_t)row * D;
    float* y = Y + (size_t)row * D;
    float ss = 0.f;
    for (int i = threadIdx.x; i < D; i += 256) { float v = x[i]; ss = fmaf(v, v, ss); }
#pragma unroll
    for (int m = 1; m < 64; m <<= 1) ss += __shfl_xor(ss, m, 64);
    __shared__ float red[4];
    if ((threadIdx.x & 63) == 0) red[threadIdx.x >> 6] = ss;
    __syncthreads();
    const float tot = red[0] + red[1] + red[2] + red[3];
    const float r = 1.0f / sqrtf(tot / (float)D + 1e-6f);
    for (int i = threadIdx.x; i < D; i += 256) y[i] = x[i] * r * w[i];
}

// ---------------------------------------------------------------- RMSNorm fp64 (fp32 weight)
__global__ __launch_bounds__(256)
void k_rmsnorm64(const double* __restrict__ X, const float* __restrict__ w,
                 double* __restrict__ Y, int D)
{
    const int row = blockIdx.x;
    const double* x = X + (size_t)row * D;
    double* y = Y + (size_t)row * D;
    double ss = 0.0;
    for (int i = threadIdx.x; i < D; i += 256) { double v = x[i]; ss = fma(v, v, ss); }
#pragma unroll
    for (int m = 1; m < 64; m <<= 1) ss += __shfl_xor(ss, m, 64);
    __shared__ double red[4];
    if ((threadIdx.x & 63) == 0) red[threadIdx.x >> 6] = ss;
    __syncthreads();
    const double tot = red[0] + red[1] + red[2] + red[3];
    const double r = 1.0 / sqrt(tot / (double)D + 1e-6);
    for (int i = threadIdx.x; i < D; i += 256) y[i] = x[i] * r * (double)w[i];
}

// ---------------------------------------------------------------- rope tables
// Bit-faithful to the reference's float32 semantics:
//   inv32 = fl32(1 / fl32(10000^(j/32)));  ang32 = fl32(fl32(pos) * inv32);
//   cos32 = fl32(cos(ang32)) via fp64 cos of the f32 angle (== correctly-rounded cosf).
__global__ __launch_bounds__(256)
void k_rope_table(const int* __restrict__ start_pos,
                  float* __restrict__ cos32, float* __restrict__ sin32)
{
    const int idx = blockIdx.x * 256 + threadIdx.x;
    if (idx >= S * 32) return;
    const int s = idx >> 5, j = idx & 31;
    const float posf = (float)(start_pos[0] + s);                 // .astype(f32), exact
    const double p64 = pow(10000.0, (double)j * 0.03125);         // j/32 exact in f32
    const float p32 = (float)p64;                                  // == powf correctly rounded
    const float inv32 = (float)(1.0 / (double)p32);                // fl32(1/p32)
    const float ang = posf * inv32;                                // single IEEE f32 multiply
    cos32[idx] = (float)cos((double)ang);                          // == cosf(ang) corr-rounded
    sin32[idx] = (float)sin((double)ang);
}

// ---------------------------------------------------------------- rope apply fp32 (value path), X:[S,heads,64]
__global__ __launch_bounds__(256)
void k_rope_apply(float* __restrict__ X, const float* __restrict__ cosT,
                  const float* __restrict__ sinT, int heads)
{
    const int idx = blockIdx.x * 256 + threadIdx.x;
    if (idx >= S * heads * 32) return;
    const int j = idx & 31;
    const int vh = idx >> 5;            // s*heads + h
    const int s = vh / heads;
    const float c = cosT[s * 32 + j], sn = sinT[s * 32 + j];
    float* p = X + (size_t)vh * 64;
    const float x1 = p[j], x2 = p[32 + j];
    p[j]      = x1 * c - x2 * sn;
    p[32 + j] = x2 * c + x1 * sn;
}

// ---------------------------------------------------------------- indexer prep fp64 (f32 rope tables):
// concat([x[64:], rope(x[:64])]) -> FWHT(128) * 128^-0.5, in place
__global__ __launch_bounds__(256)
void k_idx_prep64(double* __restrict__ X, const float* __restrict__ cosT,
                  const float* __restrict__ sinT, int heads, int nvec)
{
    const int wid = (int)((blockIdx.x * 256 + threadIdx.x) >> 6);
    const int lane = threadIdx.x & 63;
    if (wid >= nvec) return;
    const int s = wid / heads;
    double* x = X + (size_t)wid * 128;
    double y0, y1;
    if (lane < 32) {
        y0 = x[64 + 2 * lane]; y1 = x[64 + 2 * lane + 1];
    } else {
        const int j0 = (2 * (lane - 32)) & 31;
        const double a0 = x[j0], a1 = x[j0 + 1];
        const double b0 = x[j0 + 32], b1 = x[j0 + 33];
        const double c0 = (double)cosT[s * 32 + j0], c1 = (double)cosT[s * 32 + j0 + 1];
        const double s0 = (double)sinT[s * 32 + j0], s1 = (double)sinT[s * 32 + j0 + 1];
        if (lane < 48) { y0 = a0 * c0 - b0 * s0; y1 = a1 * c1 - b1 * s1; }
        else           { y0 = b0 * c0 + a0 * s0; y1 = b1 * c1 + a1 * s1; }
    }
    { const double t0 = y0 + y1, t1 = y0 - y1; y0 = t0; y1 = t1; }
#pragma unroll
    for (int m = 1; m < 64; m <<= 1) {
        const double p0 = __shfl_xor(y0, m, 64);
        const double p1 = __shfl_xor(y1, m, 64);
        if ((lane & m) == 0) { y0 = y0 + p0; y1 = y1 + p1; }
        else                 { y0 = p0 - y0; y1 = p1 - y1; }
    }
    const double SCL = 1.0 / sqrt(128.0);
    x[2 * lane] = y0 * SCL; x[2 * lane + 1] = y1 * SCL;
}

// ---------------------------------------------------------------- indexer score fp64
__global__ __launch_bounds__(256)
void k_score64(const double* __restrict__ QI, const double* __restrict__ KI,
               const double* __restrict__ Widx, double* __restrict__ SC)
{
    __shared__ double Qs[32][66];
    __shared__ double Ks[32][66];
    const int tid = threadIdx.x;
    const int tx = tid & 15, ty = tid >> 4;
    const int s0 = blockIdx.y * 64, t0 = blockIdx.x * 64;
    const int r = tid >> 2, k8 = (tid & 3) << 3;

    double sc[4][4];
#pragma unroll
    for (int i = 0; i < 4; ++i)
#pragma unroll
        for (int j = 0; j < 4; ++j) sc[i][j] = 0.0;

    for (int h = 0; h < NH; ++h) {
        double dot[4][4];
#pragma unroll
        for (int i = 0; i < 4; ++i)
#pragma unroll
            for (int j = 0; j < 4; ++j) dot[i][j] = 0.0;
        for (int kk = 0; kk < HD; kk += 32) {
            __syncthreads();
            {
                const double* qp = &QI[((size_t)(s0 + r) * NH + h) * HD + kk + k8];
                const double* kp = &KI[(size_t)(t0 + r) * HD + kk + k8];
#pragma unroll
                for (int i = 0; i < 8; ++i) { Qs[k8 + i][r] = qp[i]; Ks[k8 + i][r] = kp[i]; }
            }
            __syncthreads();
#pragma unroll 8
            for (int k = 0; k < 32; ++k) {
                double a[4], b[4];
#pragma unroll
                for (int i = 0; i < 4; ++i) a[i] = Qs[k][ty * 4 + i];
#pragma unroll
                for (int j = 0; j < 4; ++j) b[j] = Ks[k][tx * 4 + j];
#pragma unroll
                for (int i = 0; i < 4; ++i)
#pragma unroll
                    for (int j = 0; j < 4; ++j)
                        dot[i][j] = fma(a[i], b[j], dot[i][j]);
            }
        }
#pragma unroll
        for (int i = 0; i < 4; ++i) {
            const double w = Widx[(size_t)(s0 + ty * 4 + i) * NH + h];
#pragma unroll
            for (int j = 0; j < 4; ++j)
                sc[i][j] = fma(fmax(dot[i][j], 0.0), w, sc[i][j]);
        }
    }
    const double SCL = 1.0 / sqrt(128.0);
#pragma unroll
    for (int i = 0; i < 4; ++i)
#pragma unroll
        for (int j = 0; j < 4; ++j)
            SC[(size_t)(s0 + ty * 4 + i) * S + t0 + tx * 4 + j] = sc[i][j] * SCL;
}

// ---------------------------------------------------------------- fp64 top-k -> per-row selection bitmask
__global__ __launch_bounds__(256)
void k_topk64(const double* __restrict__ SC, unsigned* __restrict__ Mask)
{
    __shared__ unsigned long long u[S];
    __shared__ int cnt_sh, cg_sh, ce_sh, cut_sh;
    const int tid = threadIdx.x;
    const int row = blockIdx.x;
    for (int j = tid; j < S; j += 256) {
        unsigned long long b = (unsigned long long)__double_as_longlong(SC[(size_t)row * S + j]);
        if (b == 0x8000000000000000ull) b = 0ull;                 // -0 -> +0
        u[j] = (b & 0x8000000000000000ull) ? ~b : (b | 0x8000000000000000ull);
    }
    __syncthreads();
    unsigned long long lo = 0ull, hi = ~0ull;
    for (int it = 0; it < 64 && lo < hi; ++it) {
        const unsigned long long mid = lo + ((hi - lo) >> 1) + 1ull;
        if (tid == 0) cnt_sh = 0;
        __syncthreads();
        int c = 0;
        for (int j = tid; j < S; j += 256) c += (u[j] >= mid) ? 1 : 0;
#pragma unroll
        for (int m = 1; m < 64; m <<= 1) c += __shfl_xor(c, m, 64);
        if ((tid & 63) == 0) atomicAdd(&cnt_sh, c);
        __syncthreads();
        const int cge = cnt_sh;
        __syncthreads();
        if (cge >= TOPK) lo = mid; else hi = mid - 1ull;
    }
    const unsigned long long T = lo;
    if (tid == 0) { cg_sh = 0; ce_sh = 0; }
    __syncthreads();
    int cg = 0, ce = 0;
    for (int j = tid; j < S; j += 256) {
        cg += (u[j] > T) ? 1 : 0; ce += (u[j] == T) ? 1 : 0;
    }
#pragma unroll
    for (int m = 1; m < 64; m <<= 1) { cg += __shfl_xor(cg, m, 64); ce += __shfl_xor(ce, m, 64); }
    if ((tid & 63) == 0) { atomicAdd(&cg_sh, cg); atomicAdd(&ce_sh, ce); }
    __syncthreads();
    if (tid == 0) {
        const int need = TOPK - cg_sh;
        int cut = S - 1;
        if (ce_sh != need) {          // tie at boundary: keep lowest indices
            int acc = 0; cut = -1;
            for (int t = 0; t < S; ++t)
                if (u[t] == T) { ++acc; if (acc == need) { cut = t; break; } }
        }
        cut_sh = cut;
    }
    __syncthreads();
    const int cut = cut_sh;
    for (int w = tid; w < S / 32; w += 256) {
        unsigned bits = 0u;
#pragma unroll 4
        for (int b = 0; b < 32; ++b) {
            const int j = w * 32 + b;
            const bool sel = (u[j] > T) || ((u[j] == T) && (j <= cut));
            bits |= (sel ? 1u : 0u) << b;
        }
        Mask[(size_t)row * (S / 32) + w] = bits;
    }
}

// ---------------------------------------------------------------- dense masked flash attention per (s-tile, h), mask from bitset
__global__ __launch_bounds__(256)
void k_attn(const float* __restrict__ QN, const float* __restrict__ QR,
            const float* __restrict__ KN, const float* __restrict__ KP,
            const float* __restrict__ V, const unsigned* __restrict__ Mask,
            float* __restrict__ O)
{
    __shared__ float AB[2 * 64 * 68];   // Q-chunk @0, K-chunk @4352; V overlays [64][128]
    __shared__ float Ps[64][68];
    const int tid = threadIdx.x;
    const int tx = tid & 15, ty = tid >> 4;
    const int h = blockIdx.y;
    const int s0 = blockIdx.x * 64;
    const int r = tid >> 2;
    const int c4 = (tid & 3) << 2;

    float o[4][8];
    float mrow[4], lrow[4];
#pragma unroll
    for (int i = 0; i < 4; ++i) {
        mrow[i] = -INFINITY; lrow[i] = 0.f;
#pragma unroll
        for (int jd = 0; jd < 8; ++jd) o[i][jd] = 0.f;
    }

    for (int t0 = 0; t0 < S; t0 += 64) {
        float lg[4][4];
#pragma unroll
        for (int i = 0; i < 4; ++i)
#pragma unroll
            for (int j = 0; j < 4; ++j) lg[i][j] = 0.f;

        for (int c = 0; c < 3; ++c) {
            __syncthreads();
#pragma unroll
            for (int jj = 0; jj < 4; ++jj) {
                const int kk = c4 + 16 * jj;
                float4 va, vb;
                if (c < 2) {
                    va = *(const float4*)&QN[((size_t)(s0 + r) * NH + h) * HD + c * 64 + kk];
                    vb = *(const float4*)&KN[((size_t)(t0 + r) * NH + h) * HD + c * 64 + kk];
                } else {
                    va = *(const float4*)&QR[((size_t)(s0 + r) * NH + h) * RD + kk];
                    vb = *(const float4*)&KP[(size_t)(t0 + r) * RD + kk];
                }
                AB[(kk + 0) * 68 + r] = va.x; AB[(kk + 1) * 68 + r] = va.y;
                AB[(kk + 2) * 68 + r] = va.z; AB[(kk + 3) * 68 + r] = va.w;
                AB[4352 + (kk + 0) * 68 + r] = vb.x; AB[4352 + (kk + 1) * 68 + r] = vb.y;
                AB[4352 + (kk + 2) * 68 + r] = vb.z; AB[4352 + (kk + 3) * 68 + r] = vb.w;
            }
            __syncthreads();
#pragma unroll 16
            for (int k = 0; k < 64; ++k) {
                float a[4], b[4];
                *(float4*)a = *(const float4*)&AB[k * 68 + ty * 4];
                *(float4*)b = *(const float4*)&AB[4352 + k * 68 + tx * 4];
#pragma unroll
                for (int i = 0; i < 4; ++i)
#pragma unroll
                    for (int j = 0; j < 4; ++j)
                        lg[i][j] = fmaf(a[i], b[j], lg[i][j]);
            }
        }
        __syncthreads();   // logits done; AB free for V

        float p[4][4], mt[4], alpha[4], psum[4];
#pragma unroll
        for (int i = 0; i < 4; ++i) {
            mt[i] = -INFINITY;
            const unsigned mw = Mask[(size_t)(s0 + 4 * ty + i) * (S / 32) + (t0 >> 5) + (tx >> 3)];
            const unsigned nib = (mw >> ((tx & 7) << 2)) & 0xFu;
#pragma unroll
            for (int j = 0; j < 4; ++j) {
                if ((nib >> j) & 1u) {
                    const float l = lg[i][j] * 0.07216878364870323f;
                    p[i][j] = l;
                    mt[i] = fmaxf(mt[i], l);
                } else p[i][j] = -INFINITY;
            }
        }
#pragma unroll
        for (int m = 1; m < 16; m <<= 1)
#pragma unroll
            for (int i = 0; i < 4; ++i) mt[i] = fmaxf(mt[i], __shfl_xor(mt[i], m, 64));
#pragma unroll
        for (int i = 0; i < 4; ++i) {
            const float mnew = fmaxf(mrow[i], mt[i]);
            alpha[i] = (mnew == -INFINITY) ? 1.f : expf(mrow[i] - mnew);
            mrow[i] = mnew;
            psum[i] = 0.f;
            float pj[4];
#pragma unroll
            for (int j = 0; j < 4; ++j) {
                const float pv = (p[i][j] == -INFINITY) ? 0.f : expf(p[i][j] - mnew);
                pj[j] = pv; psum[i] += pv;
            }
            *(float4*)&Ps[4 * ty + i][tx * 4] = make_float4(pj[0], pj[1], pj[2], pj[3]);
        }
#pragma unroll
        for (int m = 1; m < 16; m <<= 1)
#pragma unroll
            for (int i = 0; i < 4; ++i) psum[i] += __shfl_xor(psum[i], m, 64);
#pragma unroll
        for (int i = 0; i < 4; ++i) {
            lrow[i] = lrow[i] * alpha[i] + psum[i];
#pragma unroll
            for (int jd = 0; jd < 8; ++jd) o[i][jd] *= alpha[i];
        }
        // stage V tile (overlays AB)
#pragma unroll
        for (int jj = 0; jj < 8; ++jj) {
            const int dq = c4 + 16 * jj;
            float4 vv = *(const float4*)&V[((size_t)(t0 + r) * NH + h) * HD + dq];
            AB[r * 128 + dq + 0] = vv.x; AB[r * 128 + dq + 1] = vv.y;
            AB[r * 128 + dq + 2] = vv.z; AB[r * 128 + dq + 3] = vv.w;
        }
        __syncthreads();
#pragma unroll 4
        for (int tc = 0; tc < 64; ++tc) {
            float pv[4];
#pragma unroll
            for (int i = 0; i < 4; ++i) pv[i] = Ps[4 * ty + i][tc];
#pragma unroll
            for (int jd = 0; jd < 8; ++jd) {
                const float vvv = AB[tc * 128 + tx + 16 * jd];
#pragma unroll
                for (int i = 0; i < 4; ++i) o[i][jd] = fmaf(pv[i], vvv, o[i][jd]);
            }
        }
    }
#pragma unroll
    for (int i = 0; i < 4; ++i) {
        const float inv = 1.0f / lrow[i];
#pragma unroll
        for (int jd = 0; jd < 8; ++jd)
            O[((size_t)(s0 + 4 * ty + i) * NH + h) * HD + tx + 16 * jd] = o[i][jd] * inv;
    }
}

// ---------------------------------------------------------------- fp64 -> fp32 cast
__global__ __launch_bounds__(256)
void k_cast64to32(const double* __restrict__ X, float* __restrict__ Y, int n)
{
    const int i = blockIdx.x * 256 + threadIdx.x;
    if (i < n) Y[i] = (float)X[i];
}

// ---------------------------------------------------------------- launcher
extern "C" void kernel_launch(void* const* d_in, const int* in_sizes, int n_in,
                              void* d_out, int out_size, void* d_ws, size_t ws_size,
                              hipStream_t stream)
{
    const float* x            = (const float*)d_in[0];
    const int*   start_pos    = (const int*)  d_in[1];
    const float* q_down_w     = (const float*)d_in[2];
    const float* q_down_b     = (const float*)d_in[3];
    const float* q_norm_w     = (const float*)d_in[4];
    const float* q_nope_up_w  = (const float*)d_in[5];
    const float* q_nope_up_b  = (const float*)d_in[6];
    const float* q_rope_up_w  = (const float*)d_in[7];
    const float* q_rope_up_b  = (const float*)d_in[8];
    const float* kv_down_w    = (const float*)d_in[9];
    const float* kv_down_b    = (const float*)d_in[10];
    const float* kv_norm_w    = (const float*)d_in[11];
    const float* k_up_w       = (const float*)d_in[12];
    const float* k_up_b       = (const float*)d_in[13];
    const float* v_up_w       = (const float*)d_in[14];
    const float* v_up_b       = (const float*)d_in[15];
    const float* k_rope_w     = (const float*)d_in[16];
    const float* k_rope_b     = (const float*)d_in[17];
    const float* out_w        = (const float*)d_in[18];
    const float* out_b        = (const float*)d_in[19];
    const float* idx_q_w      = (const float*)d_in[20];
    const float* idx_q_b      = (const float*)d_in[21];
    const float* idx_k_w      = (const float*)d_in[22];
    const float* idx_k_b      = (const float*)d_in[23];
    const float* idx_k_norm_w = (const float*)d_in[24];
    const float* idx_w_w      = (const float*)d_in[25];
    const float* idx_w_b      = (const float*)d_in[26];

    char* base = (char*)d_ws;
    size_t off = 0;
    auto alloc = [&](size_t bytes) -> void* {
        void* p = base + off; off += (bytes + 255) & ~(size_t)255; return p;
    };

    double* score64 = (double*)alloc((size_t)S * S * 8);       // 32 MB
    double* q_c64   = score64;   // alias: q_c64 dead before score64 is written
    double* qi64    = (double*)alloc((size_t)S * NH * HD * 8); // 32 MB
    double* ki64    = (double*)alloc((size_t)S * HD * 8);
    double* widx64  = (double*)alloc((size_t)S * NH * 8);
    unsigned* Mask  = (unsigned*)alloc((size_t)S * (S / 32) * 4);
    float* q_c32    = (float*)alloc((size_t)S * LR * 4);
    float* kv_c     = (float*)alloc((size_t)S * LR * 4);       // contiguous with q_c32
    float* qn       = (float*)alloc((size_t)S * NH * HD * 4);
    float* qr       = (float*)alloc((size_t)S * NH * RD * 4);
    float* kn       = (float*)alloc((size_t)S * NH * HD * 4);
    float* vv       = (float*)alloc((size_t)S * NH * HD * 4);
    float* kpe      = (float*)alloc((size_t)S * RD * 4);
    float* cos32    = (float*)alloc((size_t)S * 32 * 4);
    float* sin32    = (float*)alloc((size_t)S * 32 * 4);
    float* obuf     = q_c32;     // q_c32+kv_c = 16 MB contiguous, both dead before attention

    dim3 blk(256);
    k_rope_table<<<dim3(S * 32 / 256), blk, 0, stream>>>(start_pos, cos32, sin32);

    // ---- fp64 indexer chain with f32-faithful rope tables
    k_gemm64<float><<<dim3(LR / 64, S / 64), blk, 0, stream>>>(x, q_down_w, q_down_b, q_c64, S, LR, DM, 1.0);
    k_rmsnorm64<<<dim3(S), blk, 0, stream>>>(q_c64, q_norm_w, q_c64, LR);
    k_cast64to32<<<dim3(S * LR / 256), blk, 0, stream>>>(q_c64, q_c32, S * LR);
    k_gemm64<double><<<dim3(NH * HD / 64, S / 64), blk, 0, stream>>>(q_c64, idx_q_w, idx_q_b, qi64, S, NH * HD, LR, 1.0);
    k_gemm64<float><<<dim3(HD / 64, S / 64), blk, 0, stream>>>(x, idx_k_w, idx_k_b, ki64, S, HD, DM, 1.0);
    k_rmsnorm64<<<dim3(S), blk, 0, stream>>>(ki64, idx_k_norm_w, ki64, HD);
    k_gemm64<float><<<dim3(1, S / 64), blk, 0, stream>>>(x, idx_w_w, idx_w_b, widx64, S, NH, DM, 0.25);
    k_idx_prep64<<<dim3(S * NH / 4), blk, 0, stream>>>(qi64, cos32, sin32, NH, S * NH);
    k_idx_prep64<<<dim3(S / 4), blk, 0, stream>>>(ki64, cos32, sin32, 1, S);
    k_score64<<<dim3(S / 64, S / 64), blk, 0, stream>>>(qi64, ki64, widx64, score64);
    k_topk64<<<dim3(S), blk, 0, stream>>>(score64, Mask);

    // ---- fp32 value path
    k_gemm<<<dim3(LR / GT_N, S / GT_M), blk, 0, stream>>>(x, kv_down_w, kv_down_b, kv_c, S, LR, DM, 1.f);
    k_rmsnorm<<<dim3(S), blk, 0, stream>>>(kv_c, kv_norm_w, kv_c, LR);
    k_gemm<<<dim3(1, S / GT_M), blk, 0, stream>>>(x, k_rope_w, k_rope_b, kpe, S, RD, DM, 1.f);
    k_gemm<<<dim3(NH * HD / GT_N, S / GT_M), blk, 0, stream>>>(q_c32, q_nope_up_w, q_nope_up_b, qn, S, NH * HD, LR, 1.f);
    k_gemm<<<dim3(NH * RD / GT_N, S / GT_M), blk, 0, stream>>>(q_c32, q_rope_up_w, q_rope_up_b, qr, S, NH * RD, LR, 1.f);
    k_gemm<<<dim3(NH * HD / GT_N, S / GT_M), blk, 0, stream>>>(kv_c, k_up_w, k_up_b, kn, S, NH * HD, LR, 1.f);
    k_gemm<<<dim3(NH * HD / GT_N, S / GT_M), blk, 0, stream>>>(kv_c, v_up_w, v_up_b, vv, S, NH * HD, LR, 1.f);
    k_rope_apply<<<dim3(S * NH * 32 / 256), blk, 0, stream>>>(qr, cos32, sin32, NH);
    k_rope_apply<<<dim3(S * 32 / 256), blk, 0, stream>>>(kpe, cos32, sin32, 1);
    k_attn<<<dim3(S / 64, NH), blk, 0, stream>>>(qn, qr, kn, kpe, vv, Mask, obuf);
    k_gemm<<<dim3(DM / GT_N, S / GT_M), blk, 0, stream>>>(obuf, out_w, out_b, (float*)d_out, S, DM, NH * HD, 1.f);
}

// Round 6
// 3069.442 us; speedup vs baseline: 1.1162x; 1.1162x over previous
//
#include <hip/hip_runtime.h>
#include <hip/hip_bf16.h>
#include <math.h>

#define S 2048
#define DM 2048
#define NH 16
#define HD 128
#define RD 64
#define LR 1024
#define TOPK 512

typedef __attribute__((ext_vector_type(8))) short bf16x8;
typedef __attribute__((ext_vector_type(4))) float f32x4;

__device__ __forceinline__ unsigned short bf16h(float x) {
    __hip_bfloat16 b = __float2bfloat16(x);   // RNE
    return *reinterpret_cast<unsigned short*>(&b);
}

// ---------------------------------------------------------------- fp32 GEMM (small N fallback: kpe)
#define GT_M 128
#define GT_N 64
#define GT_K 16

__global__ __launch_bounds__(256)
void k_gemm(const float* __restrict__ A, const float* __restrict__ W,
            const float* __restrict__ bias, float* __restrict__ C,
            int M, int N, int K, float alpha)
{
    __shared__ float As[GT_K][GT_M + 4];
    __shared__ float Ws[GT_K][GT_N + 4];
    const int tid = threadIdx.x;
    const int tx = tid & 15, ty = tid >> 4;
    const int m0 = blockIdx.y * GT_M, n0 = blockIdx.x * GT_N;

    float acc[8][4];
#pragma unroll
    for (int i = 0; i < 8; ++i)
#pragma unroll
        for (int j = 0; j < 4; ++j) acc[i][j] = 0.f;

    const int ar = tid >> 1;
    const int ak = (tid & 1) << 3;
    const int wr = tid >> 2;
    const int wk = (tid & 3) << 2;

    for (int kk = 0; kk < K; kk += GT_K) {
        float4 v0 = *(const float4*)&A[(size_t)(m0 + ar) * K + kk + ak];
        float4 v1 = *(const float4*)&A[(size_t)(m0 + ar) * K + kk + ak + 4];
        float4 w0 = make_float4(0.f, 0.f, 0.f, 0.f);
        if (n0 + wr < N) w0 = *(const float4*)&W[(size_t)(n0 + wr) * K + kk + wk];
        __syncthreads();
        As[ak + 0][ar] = v0.x; As[ak + 1][ar] = v0.y; As[ak + 2][ar] = v0.z; As[ak + 3][ar] = v0.w;
        As[ak + 4][ar] = v1.x; As[ak + 5][ar] = v1.y; As[ak + 6][ar] = v1.z; As[ak + 7][ar] = v1.w;
        Ws[wk + 0][wr] = w0.x; Ws[wk + 1][wr] = w0.y; Ws[wk + 2][wr] = w0.z; Ws[wk + 3][wr] = w0.w;
        __syncthreads();
#pragma unroll
        for (int k = 0; k < GT_K; ++k) {
            float a0[8], b0[4];
            *(float4*)&a0[0] = *(const float4*)&As[k][ty * 8];
            *(float4*)&a0[4] = *(const float4*)&As[k][ty * 8 + 4];
            *(float4*)&b0[0] = *(const float4*)&Ws[k][tx * 4];
#pragma unroll
            for (int i = 0; i < 8; ++i)
#pragma unroll
                for (int j = 0; j < 4; ++j)
                    acc[i][j] = fmaf(a0[i], b0[j], acc[i][j]);
        }
    }
    const int n = n0 + tx * 4;
    if (n < N) {
#pragma unroll
        for (int i = 0; i < 8; ++i) {
            const int m = m0 + ty * 8 + i;
            float4 o;
            o.x = (acc[i][0] + bias[n + 0]) * alpha;
            o.y = (acc[i][1] + bias[n + 1]) * alpha;
            o.z = (acc[i][2] + bias[n + 2]) * alpha;
            o.w = (acc[i][3] + bias[n + 3]) * alpha;
            *(float4*)&C[(size_t)m * N + n] = o;
        }
    }
}

// ---------------------------------------------------------------- split-bf16 MFMA GEMM (value path)
// C[M,N] = (A[M,K] @ W[N,K]^T + bias) * alpha, fp32-quality via hi/lo bf16 3-term MFMA.
// Requires M%128==0, N%128==0, K%32==0.
__global__ __launch_bounds__(256)
void k_gemm_bf16s(const float* __restrict__ A, const float* __restrict__ W,
                  const float* __restrict__ bias, float* __restrict__ C,
                  int M, int N, int K, float alpha)
{
    __shared__ unsigned short AhS[128 * 32], AlS[128 * 32], WhS[128 * 32], WlS[128 * 32];
    const int tid = threadIdx.x;
    const int wid = tid >> 6, lane = tid & 63;
    const int wm = (wid >> 1) * 64, wn = (wid & 1) * 64;
    const int m0 = blockIdx.y * 128, n0 = blockIdx.x * 128;
    const int lrow = lane & 15, lkg = lane >> 4;

    f32x4 acc[4][4];
    const f32x4 zero = {0.f, 0.f, 0.f, 0.f};
#pragma unroll
    for (int mt = 0; mt < 4; ++mt)
#pragma unroll
        for (int nt = 0; nt < 4; ++nt) acc[mt][nt] = zero;

    for (int kk = 0; kk < K; kk += 32) {
        __syncthreads();
#pragma unroll
        for (int c = 0; c < 2; ++c) {
            const int chunk = tid + (c << 8);          // 0..511
            const int row = chunk >> 2, kg = chunk & 3;
            const int uidx = ((((row << 6) + (kg << 4)) ^ ((row & 7) << 4)) >> 1);
            const float* ap = &A[(size_t)(m0 + row) * K + kk + (kg << 3)];
            const float* wp = &W[(size_t)(n0 + row) * K + kk + (kg << 3)];
            float4 av0 = *(const float4*)ap; float4 av1 = *(const float4*)(ap + 4);
            float4 wv0 = *(const float4*)wp; float4 wv1 = *(const float4*)(wp + 4);
            float as[8] = {av0.x, av0.y, av0.z, av0.w, av1.x, av1.y, av1.z, av1.w};
            float ws[8] = {wv0.x, wv0.y, wv0.z, wv0.w, wv1.x, wv1.y, wv1.z, wv1.w};
            bf16x8 ah, al, wh, wl;
#pragma unroll
            for (int i = 0; i < 8; ++i) {
                unsigned short h = bf16h(as[i]);
                float hf = __uint_as_float((unsigned)h << 16);
                ah[i] = (short)h; al[i] = (short)bf16h(as[i] - hf);
                unsigned short g = bf16h(ws[i]);
                float gf = __uint_as_float((unsigned)g << 16);
                wh[i] = (short)g; wl[i] = (short)bf16h(ws[i] - gf);
            }
            *(bf16x8*)&AhS[uidx] = ah; *(bf16x8*)&AlS[uidx] = al;
            *(bf16x8*)&WhS[uidx] = wh; *(bf16x8*)&WlS[uidx] = wl;
        }
        __syncthreads();

        bf16x8 whf[4], wlf[4];
#pragma unroll
        for (int nt = 0; nt < 4; ++nt) {
            const int row = wn + nt * 16 + lrow;
            const int u = ((((row << 6) + (lkg << 4)) ^ ((row & 7) << 4)) >> 1);
            whf[nt] = *(const bf16x8*)&WhS[u];
            wlf[nt] = *(const bf16x8*)&WlS[u];
        }
#pragma unroll
        for (int mt = 0; mt < 4; ++mt) {
            const int row = wm + mt * 16 + lrow;
            const int u = ((((row << 6) + (lkg << 4)) ^ ((row & 7) << 4)) >> 1);
            bf16x8 ahf = *(const bf16x8*)&AhS[u];
            bf16x8 alf = *(const bf16x8*)&AlS[u];
#pragma unroll
            for (int nt = 0; nt < 4; ++nt) {
                acc[mt][nt] = __builtin_amdgcn_mfma_f32_16x16x32_bf16(ahf, whf[nt], acc[mt][nt], 0, 0, 0);
                acc[mt][nt] = __builtin_amdgcn_mfma_f32_16x16x32_bf16(alf, whf[nt], acc[mt][nt], 0, 0, 0);
                acc[mt][nt] = __builtin_amdgcn_mfma_f32_16x16x32_bf16(ahf, wlf[nt], acc[mt][nt], 0, 0, 0);
            }
        }
    }

#pragma unroll
    for (int mt = 0; mt < 4; ++mt)
#pragma unroll
        for (int nt = 0; nt < 4; ++nt) {
            const int col = n0 + wn + nt * 16 + lrow;
            const float b = bias[col];
            const int rbase = m0 + wm + mt * 16 + (lkg << 2);
#pragma unroll
            for (int r = 0; r < 4; ++r)
                C[(size_t)(rbase + r) * N + col] = (acc[mt][nt][r] + b) * alpha;
        }
}

// ---------------------------------------------------------------- fp64 GEMM (indexer chain)
template<typename TA>
__global__ __launch_bounds__(256)
void k_gemm64(const TA* __restrict__ A, const float* __restrict__ W,
              const float* __restrict__ bias, double* __restrict__ C,
              int M, int N, int K, double alpha)
{
    __shared__ double As[16][66];
    __shared__ double Ws[16][66];
    const int tid = threadIdx.x;
    const int tx = tid & 15, ty = tid >> 4;
    const int m0 = blockIdx.y * 64, n0 = blockIdx.x * 64;
    const int r = tid >> 2, k4 = (tid & 3) << 2;

    double acc[4][4];
#pragma unroll
    for (int i = 0; i < 4; ++i)
#pragma unroll
        for (int j = 0; j < 4; ++j) acc[i][j] = 0.0;

    for (int kk = 0; kk < K; kk += 16) {
        double av[4], wv[4];
        const TA* ap = &A[(size_t)(m0 + r) * K + kk + k4];
#pragma unroll
        for (int i = 0; i < 4; ++i) av[i] = (double)ap[i];
        if (n0 + r < N) {
            const float* wp = &W[(size_t)(n0 + r) * K + kk + k4];
#pragma unroll
            for (int i = 0; i < 4; ++i) wv[i] = (double)wp[i];
        } else {
#pragma unroll
            for (int i = 0; i < 4; ++i) wv[i] = 0.0;
        }
        __syncthreads();
#pragma unroll
        for (int i = 0; i < 4; ++i) { As[k4 + i][r] = av[i]; Ws[k4 + i][r] = wv[i]; }
        __syncthreads();
#pragma unroll 4
        for (int k = 0; k < 16; ++k) {
            double a[4], b[4];
#pragma unroll
            for (int i = 0; i < 4; ++i) a[i] = As[k][ty * 4 + i];
#pragma unroll
            for (int j = 0; j < 4; ++j) b[j] = Ws[k][tx * 4 + j];
#pragma unroll
            for (int i = 0; i < 4; ++i)
#pragma unroll
                for (int j = 0; j < 4; ++j)
                    acc[i][j] = fma(a[i], b[j], acc[i][j]);
        }
    }
    const int n = n0 + tx * 4;
    if (n < N) {
#pragma unroll
        for (int i = 0; i < 4; ++i) {
            const int m = m0 + ty * 4 + i;
#pragma unroll
            for (int j = 0; j < 4; ++j)
                C[(size_t)m * N + n + j] = (acc[i][j] + (double)bias[n + j]) * alpha;
        }
    }
}

// ---------------------------------------------------------------- RMSNorm fp32
__global__ __launch_bounds__(256)
void k_rmsnorm(const float* __restrict__ X, const float* __restrict__ w,
               float* __restrict__ Y, int D)
{
    const int row = blockIdx.x;
    const float* x = X + (size_t)row * D;
    float* y = Y + (size_t)row * D;
    float ss = 0.f;
    for (int i = threadIdx.x; i < D; i += 256) { float v = x[i]; ss = fmaf(v, v, ss); }
#pragma unroll
    for (int m = 1; m < 64; m <<= 1) ss += __shfl_xor(ss, m, 64);
    __shared__ float red[4];
    if ((threadIdx.x & 63) == 0) red[threadIdx.x >> 6] = ss;
    __syncthreads();
    const float tot = red[0] + red[1] + red[2] + red[3];
    const float r = 1.0f / sqrtf(tot / (float)D + 1e-6f);
    for (int i = threadIdx.x; i < D; i += 256) y[i] = x[i] * r * w[i];
}

// ---------------------------------------------------------------- RMSNorm fp64
__global__ __launch_bounds__(256)
void k_rmsnorm64(const double* __restrict__ X, const float* __restrict__ w,
                 double* __restrict__ Y, int D)
{
    const int row = blockIdx.x;
    const double* x = X + (size_t)row * D;
    double* y = Y + (size_t)row * D;
    double ss = 0.0;
    for (int i = threadIdx.x; i < D; i += 256) { double v = x[i]; ss = fma(v, v, ss); }
#pragma unroll
    for (int m = 1; m < 64; m <<= 1) ss += __shfl_xor(ss, m, 64);
    __shared__ double red[4];
    if ((threadIdx.x & 63) == 0) red[threadIdx.x >> 6] = ss;
    __syncthreads();
    const double tot = red[0] + red[1] + red[2] + red[3];
    const double r = 1.0 / sqrt(tot / (double)D + 1e-6);
    for (int i = threadIdx.x; i < D; i += 256) y[i] = x[i] * r * (double)w[i];
}

// ---------------------------------------------------------------- rope tables (f32-faithful)
__global__ __launch_bounds__(256)
void k_rope_table(const int* __restrict__ start_pos,
                  float* __restrict__ cos32, float* __restrict__ sin32)
{
    const int idx = blockIdx.x * 256 + threadIdx.x;
    if (idx >= S * 32) return;
    const int s = idx >> 5, j = idx & 31;
    const float posf = (float)(start_pos[0] + s);
    const double p64 = pow(10000.0, (double)j * 0.03125);
    const float p32 = (float)p64;
    const float inv32 = (float)(1.0 / (double)p32);
    const float ang = posf * inv32;
    cos32[idx] = (float)cos((double)ang);
    sin32[idx] = (float)sin((double)ang);
}

// ---------------------------------------------------------------- rope apply fp32, X:[S,heads,64]
__global__ __launch_bounds__(256)
void k_rope_apply(float* __restrict__ X, const float* __restrict__ cosT,
                  const float* __restrict__ sinT, int heads)
{
    const int idx = blockIdx.x * 256 + threadIdx.x;
    if (idx >= S * heads * 32) return;
    const int j = idx & 31;
    const int vh = idx >> 5;
    const int s = vh / heads;
    const float c = cosT[s * 32 + j], sn = sinT[s * 32 + j];
    float* p = X + (size_t)vh * 64;
    const float x1 = p[j], x2 = p[32 + j];
    p[j]      = x1 * c - x2 * sn;
    p[32 + j] = x2 * c + x1 * sn;
}

// ---------------------------------------------------------------- indexer prep fp64
__global__ __launch_bounds__(256)
void k_idx_prep64(double* __restrict__ X, const float* __restrict__ cosT,
                  const float* __restrict__ sinT, int heads, int nvec)
{
    const int wid = (int)((blockIdx.x * 256 + threadIdx.x) >> 6);
    const int lane = threadIdx.x & 63;
    if (wid >= nvec) return;
    const int s = wid / heads;
    double* x = X + (size_t)wid * 128;
    double y0, y1;
    if (lane < 32) {
        y0 = x[64 + 2 * lane]; y1 = x[64 + 2 * lane + 1];
    } else {
        const int j0 = (2 * (lane - 32)) & 31;
        const double a0 = x[j0], a1 = x[j0 + 1];
        const double b0 = x[j0 + 32], b1 = x[j0 + 33];
        const double c0 = (double)cosT[s * 32 + j0], c1 = (double)cosT[s * 32 + j0 + 1];
        const double s0 = (double)sinT[s * 32 + j0], s1 = (double)sinT[s * 32 + j0 + 1];
        if (lane < 48) { y0 = a0 * c0 - b0 * s0; y1 = a1 * c1 - b1 * s1; }
        else           { y0 = b0 * c0 + a0 * s0; y1 = b1 * c1 + a1 * s1; }
    }
    { const double t0 = y0 + y1, t1 = y0 - y1; y0 = t0; y1 = t1; }
#pragma unroll
    for (int m = 1; m < 64; m <<= 1) {
        const double p0 = __shfl_xor(y0, m, 64);
        const double p1 = __shfl_xor(y1, m, 64);
        if ((lane & m) == 0) { y0 = y0 + p0; y1 = y1 + p1; }
        else                 { y0 = p0 - y0; y1 = p1 - y1; }
    }
    const double SCL = 1.0 / sqrt(128.0);
    x[2 * lane] = y0 * SCL; x[2 * lane + 1] = y1 * SCL;
}

// ---------------------------------------------------------------- indexer score fp64
__global__ __launch_bounds__(256)
void k_score64(const double* __restrict__ QI, const double* __restrict__ KI,
               const double* __restrict__ Widx, double* __restrict__ SC)
{
    __shared__ double Qs[32][66];
    __shared__ double Ks[32][66];
    const int tid = threadIdx.x;
    const int tx = tid & 15, ty = tid >> 4;
    const int s0 = blockIdx.y * 64, t0 = blockIdx.x * 64;
    const int r = tid >> 2, k8 = (tid & 3) << 3;

    double sc[4][4];
#pragma unroll
    for (int i = 0; i < 4; ++i)
#pragma unroll
        for (int j = 0; j < 4; ++j) sc[i][j] = 0.0;

    for (int h = 0; h < NH; ++h) {
        double dot[4][4];
#pragma unroll
        for (int i = 0; i < 4; ++i)
#pragma unroll
            for (int j = 0; j < 4; ++j) dot[i][j] = 0.0;
        for (int kk = 0; kk < HD; kk += 32) {
            __syncthreads();
            {
                const double* qp = &QI[((size_t)(s0 + r) * NH + h) * HD + kk + k8];
                const double* kp = &KI[(size_t)(t0 + r) * HD + kk + k8];
#pragma unroll
                for (int i = 0; i < 8; ++i) { Qs[k8 + i][r] = qp[i]; Ks[k8 + i][r] = kp[i]; }
            }
            __syncthreads();
#pragma unroll 8
            for (int k = 0; k < 32; ++k) {
                double a[4], b[4];
#pragma unroll
                for (int i = 0; i < 4; ++i) a[i] = Qs[k][ty * 4 + i];
#pragma unroll
                for (int j = 0; j < 4; ++j) b[j] = Ks[k][tx * 4 + j];
#pragma unroll
                for (int i = 0; i < 4; ++i)
#pragma unroll
                    for (int j = 0; j < 4; ++j)
                        dot[i][j] = fma(a[i], b[j], dot[i][j]);
            }
        }
#pragma unroll
        for (int i = 0; i < 4; ++i) {
            const double w = Widx[(size_t)(s0 + ty * 4 + i) * NH + h];
#pragma unroll
            for (int j = 0; j < 4; ++j)
                sc[i][j] = fma(fmax(dot[i][j], 0.0), w, sc[i][j]);
        }
    }
    const double SCL = 1.0 / sqrt(128.0);
#pragma unroll
    for (int i = 0; i < 4; ++i)
#pragma unroll
        for (int j = 0; j < 4; ++j)
            SC[(size_t)(s0 + ty * 4 + i) * S + t0 + tx * 4 + j] = sc[i][j] * SCL;
}

// ---------------------------------------------------------------- fp64 top-k -> bitmask
__global__ __launch_bounds__(256)
void k_topk64(const double* __restrict__ SC, unsigned* __restrict__ Mask)
{
    __shared__ unsigned long long u[S];
    __shared__ int cnt_sh, cg_sh, ce_sh, cut_sh;
    const int tid = threadIdx.x;
    const int row = blockIdx.x;
    for (int j = tid; j < S; j += 256) {
        unsigned long long b = (unsigned long long)__double_as_longlong(SC[(size_t)row * S + j]);
        if (b == 0x8000000000000000ull) b = 0ull;
        u[j] = (b & 0x8000000000000000ull) ? ~b : (b | 0x8000000000000000ull);
    }
    __syncthreads();
    unsigned long long lo = 0ull, hi = ~0ull;
    for (int it = 0; it < 64 && lo < hi; ++it) {
        const unsigned long long mid = lo + ((hi - lo) >> 1) + 1ull;
        if (tid == 0) cnt_sh = 0;
        __syncthreads();
        int c = 0;
        for (int j = tid; j < S; j += 256) c += (u[j] >= mid) ? 1 : 0;
#pragma unroll
        for (int m = 1; m < 64; m <<= 1) c += __shfl_xor(c, m, 64);
        if ((tid & 63) == 0) atomicAdd(&cnt_sh, c);
        __syncthreads();
        const int cge = cnt_sh;
        __syncthreads();
        if (cge >= TOPK) lo = mid; else hi = mid - 1ull;
    }
    const unsigned long long T = lo;
    if (tid == 0) { cg_sh = 0; ce_sh = 0; }
    __syncthreads();
    int cg = 0, ce = 0;
    for (int j = tid; j < S; j += 256) {
        cg += (u[j] > T) ? 1 : 0; ce += (u[j] == T) ? 1 : 0;
    }
#pragma unroll
    for (int m = 1; m < 64; m <<= 1) { cg += __shfl_xor(cg, m, 64); ce += __shfl_xor(ce, m, 64); }
    if ((tid & 63) == 0) { atomicAdd(&cg_sh, cg); atomicAdd(&ce_sh, ce); }
    __syncthreads();
    if (tid == 0) {
        const int need = TOPK - cg_sh;
        int cut = S - 1;
        if (ce_sh != need) {
            int acc = 0; cut = -1;
            for (int t = 0; t < S; ++t)
                if (u[t] == T) { ++acc; if (acc == need) { cut = t; break; } }
        }
        cut_sh = cut;
    }
    __syncthreads();
    const int cut = cut_sh;
    for (int w = tid; w < S / 32; w += 256) {
        unsigned bits = 0u;
#pragma unroll 4
        for (int b = 0; b < 32; ++b) {
            const int j = w * 32 + b;
            const bool sel = (u[j] > T) || ((u[j] == T) && (j <= cut));
            bits |= (sel ? 1u : 0u) << b;
        }
        Mask[(size_t)row * (S / 32) + w] = bits;
    }
}

// ---------------------------------------------------------------- dense masked flash attention
__global__ __launch_bounds__(256)
void k_attn(const float* __restrict__ QN, const float* __restrict__ QR,
            const float* __restrict__ KN, const float* __restrict__ KP,
            const float* __restrict__ V, const unsigned* __restrict__ Mask,
            float* __restrict__ O)
{
    __shared__ float AB[2 * 64 * 68];
    __shared__ float Ps[64][68];
    const int tid = threadIdx.x;
    const int tx = tid & 15, ty = tid >> 4;
    const int h = blockIdx.y;
    const int s0 = blockIdx.x * 64;
    const int r = tid >> 2;
    const int c4 = (tid & 3) << 2;

    float o[4][8];
    float mrow[4], lrow[4];
#pragma unroll
    for (int i = 0; i < 4; ++i) {
        mrow[i] = -INFINITY; lrow[i] = 0.f;
#pragma unroll
        for (int jd = 0; jd < 8; ++jd) o[i][jd] = 0.f;
    }

    for (int t0 = 0; t0 < S; t0 += 64) {
        float lg[4][4];
#pragma unroll
        for (int i = 0; i < 4; ++i)
#pragma unroll
            for (int j = 0; j < 4; ++j) lg[i][j] = 0.f;

        for (int c = 0; c < 3; ++c) {
            __syncthreads();
#pragma unroll
            for (int jj = 0; jj < 4; ++jj) {
                const int kk = c4 + 16 * jj;
                float4 va, vb;
                if (c < 2) {
                    va = *(const float4*)&QN[((size_t)(s0 + r) * NH + h) * HD + c * 64 + kk];
                    vb = *(const float4*)&KN[((size_t)(t0 + r) * NH + h) * HD + c * 64 + kk];
                } else {
                    va = *(const float4*)&QR[((size_t)(s0 + r) * NH + h) * RD + kk];
                    vb = *(const float4*)&KP[(size_t)(t0 + r) * RD + kk];
                }
                AB[(kk + 0) * 68 + r] = va.x; AB[(kk + 1) * 68 + r] = va.y;
                AB[(kk + 2) * 68 + r] = va.z; AB[(kk + 3) * 68 + r] = va.w;
                AB[4352 + (kk + 0) * 68 + r] = vb.x; AB[4352 + (kk + 1) * 68 + r] = vb.y;
                AB[4352 + (kk + 2) * 68 + r] = vb.z; AB[4352 + (kk + 3) * 68 + r] = vb.w;
            }
            __syncthreads();
#pragma unroll 16
            for (int k = 0; k < 64; ++k) {
                float a[4], b[4];
                *(float4*)a = *(const float4*)&AB[k * 68 + ty * 4];
                *(float4*)b = *(const float4*)&AB[4352 + k * 68 + tx * 4];
#pragma unroll
                for (int i = 0; i < 4; ++i)
#pragma unroll
                    for (int j = 0; j < 4; ++j)
                        lg[i][j] = fmaf(a[i], b[j], lg[i][j]);
            }
        }
        __syncthreads();

        float p[4][4], mt[4], alpha[4], psum[4];
#pragma unroll
        for (int i = 0; i < 4; ++i) {
            mt[i] = -INFINITY;
            const unsigned mw = Mask[(size_t)(s0 + 4 * ty + i) * (S / 32) + (t0 >> 5) + (tx >> 3)];
            const unsigned nib = (mw >> ((tx & 7) << 2)) & 0xFu;
#pragma unroll
            for (int j = 0; j < 4; ++j) {
                if ((nib >> j) & 1u) {
                    const float l = lg[i][j] * 0.07216878364870323f;
                    p[i][j] = l;
                    mt[i] = fmaxf(mt[i], l);
                } else p[i][j] = -INFINITY;
            }
        }
#pragma unroll
        for (int m = 1; m < 16; m <<= 1)
#pragma unroll
            for (int i = 0; i < 4; ++i) mt[i] = fmaxf(mt[i], __shfl_xor(mt[i], m, 64));
#pragma unroll
        for (int i = 0; i < 4; ++i) {
            const float mnew = fmaxf(mrow[i], mt[i]);
            alpha[i] = (mnew == -INFINITY) ? 1.f : expf(mrow[i] - mnew);
            mrow[i] = mnew;
            psum[i] = 0.f;
            float pj[4];
#pragma unroll
            for (int j = 0; j < 4; ++j) {
                const float pv = (p[i][j] == -INFINITY) ? 0.f : expf(p[i][j] - mnew);
                pj[j] = pv; psum[i] += pv;
            }
            *(float4*)&Ps[4 * ty + i][tx * 4] = make_float4(pj[0], pj[1], pj[2], pj[3]);
        }
#pragma unroll
        for (int m = 1; m < 16; m <<= 1)
#pragma unroll
            for (int i = 0; i < 4; ++i) psum[i] += __shfl_xor(psum[i], m, 64);
#pragma unroll
        for (int i = 0; i < 4; ++i) {
            lrow[i] = lrow[i] * alpha[i] + psum[i];
#pragma unroll
            for (int jd = 0; jd < 8; ++jd) o[i][jd] *= alpha[i];
        }
#pragma unroll
        for (int jj = 0; jj < 8; ++jj) {
            const int dq = c4 + 16 * jj;
            float4 vv = *(const float4*)&V[((size_t)(t0 + r) * NH + h) * HD + dq];
            AB[r * 128 + dq + 0] = vv.x; AB[r * 128 + dq + 1] = vv.y;
            AB[r * 128 + dq + 2] = vv.z; AB[r * 128 + dq + 3] = vv.w;
        }
        __syncthreads();
#pragma unroll 4
        for (int tc = 0; tc < 64; ++tc) {
            float pv[4];
#pragma unroll
            for (int i = 0; i < 4; ++i) pv[i] = Ps[4 * ty + i][tc];
#pragma unroll
            for (int jd = 0; jd < 8; ++jd) {
                const float vvv = AB[tc * 128 + tx + 16 * jd];
#pragma unroll
                for (int i = 0; i < 4; ++i) o[i][jd] = fmaf(pv[i], vvv, o[i][jd]);
            }
        }
    }
#pragma unroll
    for (int i = 0; i < 4; ++i) {
        const float inv = 1.0f / lrow[i];
#pragma unroll
        for (int jd = 0; jd < 8; ++jd)
            O[((size_t)(s0 + 4 * ty + i) * NH + h) * HD + tx + 16 * jd] = o[i][jd] * inv;
    }
}

// ---------------------------------------------------------------- fp64 -> fp32 cast
__global__ __launch_bounds__(256)
void k_cast64to32(const double* __restrict__ X, float* __restrict__ Y, int n)
{
    const int i = blockIdx.x * 256 + threadIdx.x;
    if (i < n) Y[i] = (float)X[i];
}

// ---------------------------------------------------------------- launcher
extern "C" void kernel_launch(void* const* d_in, const int* in_sizes, int n_in,
                              void* d_out, int out_size, void* d_ws, size_t ws_size,
                              hipStream_t stream)
{
    const float* x            = (const float*)d_in[0];
    const int*   start_pos    = (const int*)  d_in[1];
    const float* q_down_w     = (const float*)d_in[2];
    const float* q_down_b     = (const float*)d_in[3];
    const float* q_norm_w     = (const float*)d_in[4];
    const float* q_nope_up_w  = (const float*)d_in[5];
    const float* q_nope_up_b  = (const float*)d_in[6];
    const float* q_rope_up_w  = (const float*)d_in[7];
    const float* q_rope_up_b  = (const float*)d_in[8];
    const float* kv_down_w    = (const float*)d_in[9];
    const float* kv_down_b    = (const float*)d_in[10];
    const float* kv_norm_w    = (const float*)d_in[11];
    const float* k_up_w       = (const float*)d_in[12];
    const float* k_up_b       = (const float*)d_in[13];
    const float* v_up_w       = (const float*)d_in[14];
    const float* v_up_b       = (const float*)d_in[15];
    const float* k_rope_w     = (const float*)d_in[16];
    const float* k_rope_b     = (const float*)d_in[17];
    const float* out_w        = (const float*)d_in[18];
    const float* out_b        = (const float*)d_in[19];
    const float* idx_q_w      = (const float*)d_in[20];
    const float* idx_q_b      = (const float*)d_in[21];
    const float* idx_k_w      = (const float*)d_in[22];
    const float* idx_k_b      = (const float*)d_in[23];
    const float* idx_k_norm_w = (const float*)d_in[24];
    const float* idx_w_w      = (const float*)d_in[25];
    const float* idx_w_b      = (const float*)d_in[26];

    char* base = (char*)d_ws;
    size_t off = 0;
    auto alloc = [&](size_t bytes) -> void* {
        void* p = base + off; off += (bytes + 255) & ~(size_t)255; return p;
    };

    double* score64 = (double*)alloc((size_t)S * S * 8);       // 32 MB
    double* q_c64   = score64;   // alias: q_c64 dead before score64 is written
    double* qi64    = (double*)alloc((size_t)S * NH * HD * 8); // 32 MB
    double* ki64    = (double*)alloc((size_t)S * HD * 8);
    double* widx64  = (double*)alloc((size_t)S * NH * 8);
    unsigned* Mask  = (unsigned*)alloc((size_t)S * (S / 32) * 4);
    float* q_c32    = (float*)alloc((size_t)S * LR * 4);
    float* kv_c     = (float*)alloc((size_t)S * LR * 4);       // contiguous with q_c32
    float* qn       = (float*)alloc((size_t)S * NH * HD * 4);
    float* qr       = (float*)alloc((size_t)S * NH * RD * 4);
    float* kn       = (float*)alloc((size_t)S * NH * HD * 4);
    float* vv       = (float*)alloc((size_t)S * NH * HD * 4);
    float* kpe      = (float*)alloc((size_t)S * RD * 4);
    float* cos32    = (float*)alloc((size_t)S * 32 * 4);
    float* sin32    = (float*)alloc((size_t)S * 32 * 4);
    float* obuf     = q_c32;     // q_c32+kv_c = 16 MB contiguous, both dead before attention

    dim3 blk(256);
    k_rope_table<<<dim3(S * 32 / 256), blk, 0, stream>>>(start_pos, cos32, sin32);

    // ---- fp64 indexer chain with f32-faithful rope tables
    k_gemm64<float><<<dim3(LR / 64, S / 64), blk, 0, stream>>>(x, q_down_w, q_down_b, q_c64, S, LR, DM, 1.0);
    k_rmsnorm64<<<dim3(S), blk, 0, stream>>>(q_c64, q_norm_w, q_c64, LR);
    k_cast64to32<<<dim3(S * LR / 256), blk, 0, stream>>>(q_c64, q_c32, S * LR);
    k_gemm64<double><<<dim3(NH * HD / 64, S / 64), blk, 0, stream>>>(q_c64, idx_q_w, idx_q_b, qi64, S, NH * HD, LR, 1.0);
    k_gemm64<float><<<dim3(HD / 64, S / 64), blk, 0, stream>>>(x, idx_k_w, idx_k_b, ki64, S, HD, DM, 1.0);
    k_rmsnorm64<<<dim3(S), blk, 0, stream>>>(ki64, idx_k_norm_w, ki64, HD);
    k_gemm64<float><<<dim3(1, S / 64), blk, 0, stream>>>(x, idx_w_w, idx_w_b, widx64, S, NH, DM, 0.25);
    k_idx_prep64<<<dim3(S * NH / 4), blk, 0, stream>>>(qi64, cos32, sin32, NH, S * NH);
    k_idx_prep64<<<dim3(S / 4), blk, 0, stream>>>(ki64, cos32, sin32, 1, S);
    k_score64<<<dim3(S / 64, S / 64), blk, 0, stream>>>(qi64, ki64, widx64, score64);
    k_topk64<<<dim3(S), blk, 0, stream>>>(score64, Mask);

    // ---- value path: split-bf16 MFMA GEMMs (fp32-quality)
    k_gemm_bf16s<<<dim3(LR / 128, S / 128), blk, 0, stream>>>(x, kv_down_w, kv_down_b, kv_c, S, LR, DM, 1.f);
    k_rmsnorm<<<dim3(S), blk, 0, stream>>>(kv_c, kv_norm_w, kv_c, LR);
    k_gemm<<<dim3(1, S / GT_M), blk, 0, stream>>>(x, k_rope_w, k_rope_b, kpe, S, RD, DM, 1.f);
    k_gemm_bf16s<<<dim3(NH * HD / 128, S / 128), blk, 0, stream>>>(q_c32, q_nope_up_w, q_nope_up_b, qn, S, NH * HD, LR, 1.f);
    k_gemm_bf16s<<<dim3(NH * RD / 128, S / 128), blk, 0, stream>>>(q_c32, q_rope_up_w, q_rope_up_b, qr, S, NH * RD, LR, 1.f);
    k_gemm_bf16s<<<dim3(NH * HD / 128, S / 128), blk, 0, stream>>>(kv_c, k_up_w, k_up_b, kn, S, NH * HD, LR, 1.f);
    k_gemm_bf16s<<<dim3(NH * HD / 128, S / 128), blk, 0, stream>>>(kv_c, v_up_w, v_up_b, vv, S, NH * HD, LR, 1.f);
    k_rope_apply<<<dim3(S * NH * 32 / 256), blk, 0, stream>>>(qr, cos32, sin32, NH);
    k_rope_apply<<<dim3(S * 32 / 256), blk, 0, stream>>>(kpe, cos32, sin32, 1);
    k_attn<<<dim3(S / 64, NH), blk, 0, stream>>>(qn, qr, kn, kpe, vv, Mask, obuf);
    k_gemm_bf16s<<<dim3(DM / 128, S / 128), blk, 0, stream>>>(obuf, out_w, out_b, (float*)d_out, S, DM, NH * HD, 1.f);
}